// Round 11
// baseline (426.120 us; speedup 1.0000x reference)
//
#include <hip/hip_runtime.h>
#include <hip/hip_bf16.h>
#include <math.h>

#define NC 24
#define NP 48
#define NI 6
#define BATCH 256
#define DIM 512
#define NELEM (BATCH*DIM)     // 131072
#define PROWS (BATCH*NC)      // 6144

typedef __bf16 bf16x8 __attribute__((ext_vector_type(8)));
typedef unsigned short u16x8 __attribute__((ext_vector_type(8)));
typedef float f32x4 __attribute__((ext_vector_type(4)));
using bf16 = __hip_bfloat16;

struct bq8 { __hip_bfloat162 a, b; };   // 8-byte LDS write

__device__ __forceinline__ void gld_lds16(const void* g, void* l) {
  __builtin_amdgcn_global_load_lds(
      (const __attribute__((address_space(1))) void*)g,
      (__attribute__((address_space(3))) void*)l, 16, 0, 0);
}

__device__ __forceinline__ float fast_tanh(float x) {
  float u = __expf(2.0f * x);
  float r = __builtin_amdgcn_rcpf(u + 1.0f);
  return __builtin_fmaf(-2.0f, r, 1.0f);
}

__device__ __forceinline__ float bfu(unsigned short u) {
  union { unsigned int i; float f; } v; v.i = ((unsigned)u) << 16; return v.f;
}

// ---- constants: Tbf[48][32] (T^T, c-pad), Abf[32][64] (A24, pads), a1[24],
//      rs[p] = sum_q M[p][q], wv, scales(+sumw), zbias ----
__global__ void k_setup(const float* __restrict__ t_span, bf16* __restrict__ Tbf,
                        bf16* __restrict__ Abf, float* __restrict__ a1,
                        float* __restrict__ rs, float* __restrict__ wv,
                        float* __restrict__ scales, float* __restrict__ zbias,
                        float* __restrict__ out) {
  __shared__ double Tsh[NC][NP];
  __shared__ double Ashd[NC][NP];
  __shared__ double a1sh[NC];
  __shared__ double wsh[NP];
  int tid = threadIdx.x;   // 64
  for (int idx = tid; idx < NC*NP; idx += 64) {
    int c = idx / NP, p = idx % NP;
    Tsh[c][p] = cos((double)c * (M_PI * ((double)p + 0.5) / NP));
  }
  for (int idx = tid; idx < 32*64; idx += 64) Abf[idx] = __float2bfloat16(0.f);
  for (int idx = tid; idx < 48*32; idx += 64) Tbf[idx] = __float2bfloat16(0.f);
  __syncthreads();
  if (tid < NP) {
    int q = tid;
    double V[NC], K[NC];
    for (int c = 0; c < NC; c++) V[c] = (2.0/NP) * Tsh[c][q];
    V[0] *= 0.5;
    double s = 0.0;
    for (int n = 1; n < NC; n++) {
      double hi = (n+1 < NC) ? V[n+1] : 0.0;
      K[n] = (V[n-1] - hi) / (2.0*n);
      s += (n & 1) ? -K[n] : K[n];
    }
    K[0] = -s;
    double wsum = 0.0;
    for (int c = 0; c < NC; c++) wsum += K[c];
    wv[q] = (float)wsum;
    wsh[q] = wsum;
    for (int c = 0; c < NC; c++) {
      Ashd[c][q] = K[c];
      Abf[c*64 + q] = __float2bfloat16((float)K[c]);
    }
  }
  __syncthreads();
  if (tid < NC) {
    double s = 0.0;
    for (int q = 0; q < NP; q++) s += Ashd[tid][q];
    a1sh[tid] = s;
    a1[tid] = (float)s;
  }
  __syncthreads();
  if (tid < NP) {
    int p = tid;
    double r = 0.0;
    for (int c = 0; c < NC; c++) r += Tsh[c][p] * a1sh[c];
    rs[p] = (float)r;
    for (int c = 0; c < NC; c++) Tbf[p*32 + c] = __float2bfloat16((float)Tsh[c][p]);
  }
  if (tid == 0) {
    double s = 0.0;
    for (int q = 0; q < NP; q++) s += wsh[q];
    scales[6] = (float)s;                        // sumw
  }
  for (int idx = tid; idx < DIM; idx += 64) zbias[idx] = 0.f;
  if (tid < NI) scales[tid] = 0.5f*(t_span[tid+1]-t_span[tid]);
  if (tid < NI+1) out[tid] = t_span[tid];
}

// ---- weights -> bf16: W1T[h][d], W2T[d][h], W2bf[h][d] ----
__global__ void k_wt(const float* __restrict__ W1, const float* __restrict__ W2,
                     bf16* __restrict__ W1T, bf16* __restrict__ W2T,
                     bf16* __restrict__ W2bf) {
  int idx = blockIdx.x*256 + threadIdx.x;
  int k = idx >> 9, n = idx & 511;
  W1T[n*DIM + k] = __float2bfloat16(W1[idx]);
  W2T[n*DIM + k] = __float2bfloat16(W2[idx]);
  W2bf[idx]      = __float2bfloat16(W2[idx]);
}

// ---- bb[h] = sum_d b2[d] * W1[d][h] ----
__global__ void k_bb(const float* __restrict__ W1, const float* __restrict__ b2,
                     float* __restrict__ bb) {
  int h = blockIdx.x*256 + threadIdx.x;
  float s = 0.f;
  for (int d = 0; d < DIM; d++) s = fmaf(b2[d], W1[d*DIM + h], s);
  bb[h] = s;
}

// ---- init: y0, y0bf, traj[0] ----
__global__ void k_init(const float* __restrict__ y_init, float* __restrict__ y0,
                       bf16* __restrict__ y0bf, float* __restrict__ traj0) {
  int i = blockIdx.x*256 + threadIdx.x;
  float v = y_init[i];
  y0[i] = v; traj0[i] = v;
  y0bf[i] = __float2bfloat16(v);
}

// ---- generic bf16 MFMA GEMM: tile 128x64, BK=64, dbuf, counted vmcnt ----
// EPI 1: outb = bf16(acc + bias)
// EPI 2: outf = acc + bias (f32, =C); outb = bf16(tanh(C)) (=H1)
template<int EPI>
__global__ __launch_bounds__(256, 3) void k_gemm(const bf16* __restrict__ A,
    const bf16* __restrict__ BT, const float* __restrict__ bias,
    bf16* __restrict__ outb, float* __restrict__ outf) {
  __shared__ bf16 sA[2][128*64];
  __shared__ bf16 sB[2][64*64];
  int tid = threadIdx.x;
  int lane = tid & 63, wid = tid >> 6;
  int q8 = gridDim.x >> 3;
  int tl = (blockIdx.x & 7)*q8 + (blockIdx.x >> 3);
  int bm = tl >> 3, bn = tl & 7;
  int row0 = bm*128, col0 = bn*64;
  int wr = wid >> 1, wc = wid & 1;
  int r16 = lane & 15, g = lane >> 4;

  f32x4 acc[4][2];
  #pragma unroll
  for (int m = 0; m < 4; m++)
    #pragma unroll
    for (int n = 0; n < 2; n++)
      acc[m][n] = {0.f, 0.f, 0.f, 0.f};

  auto stage = [&](int buf, int k0) {
    #pragma unroll
    for (int j = 0; j < 4; j++) {
      int cid = wid*64 + lane + j*256;
      int r = cid >> 3;
      int c = (cid & 7) ^ (r & 7);
      gld_lds16(A + (size_t)(row0 + r)*DIM + k0 + c*8,
                (char*)&sA[buf][0] + wid*1024 + j*4096);
    }
    #pragma unroll
    for (int j = 0; j < 2; j++) {
      int cid = wid*64 + lane + j*256;
      int r = cid >> 3;
      int c = (cid & 7) ^ (r & 7);
      gld_lds16(BT + (size_t)(col0 + r)*DIM + k0 + c*8,
                (char*)&sB[buf][0] + wid*1024 + j*4096);
    }
  };

  stage(0, 0);
  int cur = 0;
  for (int k0 = 0; k0 < DIM; k0 += 64) {
    if (k0 + 64 < DIM) {
      stage(cur ^ 1, k0 + 64);
      asm volatile("s_waitcnt vmcnt(6)" ::: "memory");
    } else {
      asm volatile("s_waitcnt vmcnt(0)" ::: "memory");
    }
    __builtin_amdgcn_s_barrier();
    #pragma unroll
    for (int kk = 0; kk < 2; kk++) {
      bf16x8 af[4], bfr[2];
      #pragma unroll
      for (int m = 0; m < 4; m++) {
        int r = wr*64 + m*16 + r16;
        af[m] = *(const bf16x8*)(&sA[cur][0] + r*64 + (((kk*4+g) ^ (r&7))*8));
      }
      #pragma unroll
      for (int n = 0; n < 2; n++) {
        int r = wc*32 + n*16 + r16;
        bfr[n] = *(const bf16x8*)(&sB[cur][0] + r*64 + (((kk*4+g) ^ (r&7))*8));
      }
      #pragma unroll
      for (int m = 0; m < 4; m++)
        #pragma unroll
        for (int n = 0; n < 2; n++)
          acc[m][n] = __builtin_amdgcn_mfma_f32_16x16x32_bf16(af[m], bfr[n], acc[m][n], 0, 0, 0);
    }
    __builtin_amdgcn_s_barrier();
    cur ^= 1;
  }

  #pragma unroll
  for (int m = 0; m < 4; m++) {
    int rowb = row0 + wr*64 + m*16 + g*4;
    #pragma unroll
    for (int n = 0; n < 2; n++) {
      int col = col0 + wc*32 + n*16 + r16;
      float bv = bias[col];
      #pragma unroll
      for (int r = 0; r < 4; r++) {
        float v = acc[m][n][r] + bv;
        size_t idx = (size_t)(rowb + r)*DIM + col;
        if constexpr (EPI == 1) {
          outb[idx] = __float2bfloat16(v);
        } else {
          outf[idx] = v;
          outb[idx] = __float2bfloat16(fast_tanh(v));
        }
      }
    }
  }
}

// ---- k_iter: one Picard iteration in 24-coeff space. Tile: 2 b's x 128 h.
// MODE 0 (FIRST): G24 = a1 (x) (H1.W21) computed in-kernel; phases B,C -> P'
// MODE 1 (MID):   phase A: G24 = P.W21 (48x128 MFMA GEMM, 3-buf 2-ahead pipeline);
//                 B: Z = C+sc(T.G24+rs*bb); C: P' = A24.tanh(Z)
// MODE 2 (FIN):   phases A,B -> Hw = sum_p wv[p]*tanh(Z[p])
// LDS: staging sA[3][48x64] @0 (18K), sB[3][128x64] @18432 (48K) = 66K
//      overlay (post-phase-A): sGT[b=2][h=128][c=32] @0 (16K, swz slot^((h>>1)&3));
//               sHT[b=2][h=128][p=64] @16384 (32K, swz ^((h&7)<<4)); sH1 @16384 (FIRST)
template<int MODE>
__global__ __launch_bounds__(256, 2) void k_iter(
    const bf16* __restrict__ Pin, const bf16* __restrict__ H1,
    const bf16* __restrict__ W21T, const float* __restrict__ Cg,
    const float* __restrict__ bbg, const bf16* __restrict__ Tbf,
    const bf16* __restrict__ Abf, const float* __restrict__ a1,
    const float* __restrict__ rsg, const float* __restrict__ wvg,
    const float* __restrict__ scales, int t, bf16* __restrict__ outp) {
  __shared__ char smem[67584];
  int tid = threadIdx.x;
  int lane = tid & 63, wid = tid >> 6;
  int r16 = lane & 15, g = lane >> 4;
  int q8 = gridDim.x >> 3;
  int tl = (blockIdx.x & 7)*q8 + (blockIdx.x >> 3);
  int bm = tl >> 2, bn = tl & 3;
  int col0 = bn*128;
  int bglob0 = bm*2;

  if constexpr (MODE != 0) {
    // ---- Phase A: G24 = P.W21, rows [bm*48, +48), cols [col0, +128) ----
    int row0 = bm*48;
    f32x4 acc[3][2];
    #pragma unroll
    for (int m = 0; m < 3; m++)
      #pragma unroll
      for (int n = 0; n < 2; n++)
        acc[m][n] = {0.f, 0.f, 0.f, 0.f};

    auto stage = [&](int buf, int k0) {
      #pragma unroll
      for (int j = 0; j < 2; j++) {         // A: 384 chunks = 2 x (4 waves x 48 lanes)
        if (lane < 48) {
          int cid = j*192 + wid*48 + lane;
          int r = cid >> 3, cc = (cid & 7) ^ (r & 7);
          gld_lds16(Pin + (size_t)(row0 + r)*DIM + k0 + cc*8,
                    smem + buf*6144 + j*3072 + wid*768);
        }
      }
      #pragma unroll
      for (int j = 0; j < 4; j++) {         // B: 1024 chunks = 4 x 256
        int cid = j*256 + wid*64 + lane;
        int r = cid >> 3, cc = (cid & 7) ^ (r & 7);
        gld_lds16(W21T + (size_t)(col0 + r)*DIM + k0 + cc*8,
                  smem + 18432 + buf*16384 + j*4096 + wid*1024);
      }
    };

    stage(0, 0);                            // 6 loads in flight
    stage(1, 64);                           // 12 in flight (2-ahead)
    for (int ks = 0; ks < 8; ks++) {
      if (ks < 6) {
        stage((ks+2)%3, (ks+2)*64);
        asm volatile("s_waitcnt vmcnt(12)" ::: "memory");  // tile ks landed; 2 newer in flight
      } else if (ks == 6) {
        asm volatile("s_waitcnt vmcnt(6)" ::: "memory");
      } else {
        asm volatile("s_waitcnt vmcnt(0)" ::: "memory");
      }
      __builtin_amdgcn_s_barrier();
      int cur = ks % 3;
      const char* sAc = smem + cur*6144;
      const char* sBc = smem + 18432 + cur*16384;
      #pragma unroll
      for (int kk = 0; kk < 2; kk++) {
        bf16x8 af[3], bfr[2];
        #pragma unroll
        for (int m = 0; m < 3; m++) {
          int r = m*16 + r16;
          af[m] = *(const bf16x8*)(sAc + r*128 + ((kk*4+g) ^ (r&7))*16);
        }
        #pragma unroll
        for (int n = 0; n < 2; n++) {
          int r = wid*32 + n*16 + r16;
          bfr[n] = *(const bf16x8*)(sBc + r*128 + ((kk*4+g) ^ (r&7))*16);
        }
        #pragma unroll
        for (int m = 0; m < 3; m++)
          #pragma unroll
          for (int n = 0; n < 2; n++)
            acc[m][n] = __builtin_amdgcn_mfma_f32_16x16x32_bf16(af[m], bfr[n], acc[m][n], 0, 0, 0);
      }
      __builtin_amdgcn_s_barrier();
    }

    // write G24 -> sGT[b][h][c] (rows of 64B, slot swizzle)
    #pragma unroll
    for (int m = 0; m < 3; m++) {
      int rowf = m*16 + g*4;                // 4 consecutive c via regs; never crosses b
      int b_loc = rowf >= 24 ? 1 : 0;
      int c0 = rowf - b_loc*24;
      int slot = c0 >> 3;
      int inb  = (c0*2) & 15;
      #pragma unroll
      for (int n = 0; n < 2; n++) {
        int h = wid*32 + n*16 + r16;
        char* ad = smem + b_loc*8192 + h*64 + (((slot ^ ((h>>1)&3)) << 4) | inb);
        bq8 v;
        v.a = __hip_bfloat162{__float2bfloat16(acc[m][n][0]), __float2bfloat16(acc[m][n][1])};
        v.b = __hip_bfloat162{__float2bfloat16(acc[m][n][2]), __float2bfloat16(acc[m][n][3])};
        *(bq8*)ad = v;
      }
    }
  } else {
    // ---- FIRST: sH1 <- H1 rows; per-thread g1 = H1[b].W21[:,h]; sGT = a1 (x) g1 ----
    bf16* sH1 = (bf16*)(smem + 16384);
    #pragma unroll
    for (int j = 0; j < 4; j++) {
      int e = j*256 + tid;                  // [0,1024)
      int b = e >> 9, k = e & 511;
      sH1[e] = H1[(size_t)(bglob0 + b)*DIM + k];
    }
    __syncthreads();
    int b = tid >> 7, hl = tid & 127;
    int hg = col0 + hl;
    const bf16* wrow = W21T + (size_t)hg*DIM;
    const bf16* hrow = sH1 + b*512;
    float g1 = 0.f;
    for (int ks = 0; ks < 64; ks++) {
      u16x8 w8 = *(const u16x8*)(wrow + ks*8);
      u16x8 h8 = *(const u16x8*)(hrow + ks*8);
      #pragma unroll
      for (int i = 0; i < 8; i++)
        g1 = fmaf(bfu(h8[i]), bfu(w8[i]), g1);
    }
    __syncthreads();
    int rot = ((hl>>1)&3) << 4;
    #pragma unroll
    for (int c = 0; c < NC; c++) {
      int lb = c*2;
      char* ad = smem + b*8192 + hl*64 + ((( (lb>>4) << 4) ^ rot) | (lb & 15));
      *(bf16*)ad = __float2bfloat16(a1[c]*g1);
    }
  }

  // zero sGT pad slot (c 24..31) and barrier before phase B
  if (tid < 256) {
    int bz = tid >> 7, hz = tid & 127;
    *(f32x4*)(smem + bz*8192 + hz*64 + ((3 ^ ((hz>>1)&3)) << 4)) = f32x4{0.f,0.f,0.f,0.f};
  }
  __syncthreads();

  // ---- Phase B: Z = C + sc*(T48.G24 + rs*bb); tanh ----
  int b_w = wid >> 1;
  int h0 = (wid & 1) << 6;
  int bglob = bglob0 + b_w;
  float sc = scales[t];

  f32x4 acc2[3][4];
  #pragma unroll
  for (int pt = 0; pt < 3; pt++)
    #pragma unroll
    for (int n2 = 0; n2 < 4; n2++)
      acc2[pt][n2] = {0.f, 0.f, 0.f, 0.f};
  {
    bf16x8 afT[3];
    #pragma unroll
    for (int pt = 0; pt < 3; pt++)
      afT[pt] = *(const bf16x8*)(Tbf + (pt*16 + r16)*32 + g*8);
    #pragma unroll
    for (int n2 = 0; n2 < 4; n2++) {
      int h = h0 + n2*16 + r16;
      bf16x8 b8 = *(const bf16x8*)(smem + b_w*8192 + h*64 + ((g ^ ((h>>1)&3)) << 4));
      #pragma unroll
      for (int pt = 0; pt < 3; pt++)
        acc2[pt][n2] = __builtin_amdgcn_mfma_f32_16x16x32_bf16(afT[pt], b8, acc2[pt][n2], 0, 0, 0);
    }
  }

  float rsv[12];
  #pragma unroll
  for (int pt = 0; pt < 3; pt++)
    #pragma unroll
    for (int r = 0; r < 4; r++)
      rsv[pt*4+r] = rsg[pt*16 + g*4 + r];

  if constexpr (MODE == 2) {
    // FIN: Hw = sum_p wv[p]*tanh(Z[p])
    float wvv[12];
    #pragma unroll
    for (int pt = 0; pt < 3; pt++)
      #pragma unroll
      for (int r = 0; r < 4; r++)
        wvv[pt*4+r] = wvg[pt*16 + g*4 + r];
    #pragma unroll
    for (int n2 = 0; n2 < 4; n2++) {
      int hg2 = col0 + h0 + n2*16 + r16;
      float cv = Cg[(size_t)bglob*DIM + hg2];
      float bbv = bbg[hg2];
      float hw = 0.f;
      #pragma unroll
      for (int pt = 0; pt < 3; pt++)
        #pragma unroll
        for (int r = 0; r < 4; r++) {
          float z = fmaf(sc, fmaf(rsv[pt*4+r], bbv, acc2[pt][n2][r]), cv);
          hw = fmaf(wvv[pt*4+r], fast_tanh(z), hw);
        }
      hw += __shfl_xor(hw, 16);
      hw += __shfl_xor(hw, 32);
      if (g == 0)
        outp[(size_t)bglob*DIM + hg2] = __float2bfloat16(hw);
    }
    return;
  } else {
    // tanh -> sHT[b][h][p]
    #pragma unroll
    for (int n2 = 0; n2 < 4; n2++) {
      int h = h0 + n2*16 + r16;
      int hg2 = col0 + h;
      float cv = Cg[(size_t)bglob*DIM + hg2];
      float bbv = bbg[hg2];
      #pragma unroll
      for (int pt = 0; pt < 3; pt++) {
        int p0 = pt*16 + g*4;
        float th[4];
        #pragma unroll
        for (int r = 0; r < 4; r++) {
          float z = fmaf(sc, fmaf(rsv[pt*4+r], bbv, acc2[pt][n2][r]), cv);
          th[r] = fast_tanh(z);
        }
        char* ad = smem + 16384 + b_w*16384 + h*128 + ((p0*2) ^ ((h&7)<<4));
        bq8 v;
        v.a = __hip_bfloat162{__float2bfloat16(th[0]), __float2bfloat16(th[1])};
        v.b = __hip_bfloat162{__float2bfloat16(th[2]), __float2bfloat16(th[3])};
        *(bq8*)ad = v;
      }
    }
    // zero sHT pad p 48..63
    if (tid < 256) {
      int bz = tid >> 7, hz = tid & 127;
      char* base = smem + 16384 + bz*16384 + hz*128;
      *(f32x4*)(base + (96  ^ ((hz&7)<<4))) = f32x4{0.f,0.f,0.f,0.f};
      *(f32x4*)(base + (112 ^ ((hz&7)<<4))) = f32x4{0.f,0.f,0.f,0.f};
    }
    __syncthreads();

    // ---- Phase C: P' = A24.tanh(Z) ----
    f32x4 acc3[2][4];
    #pragma unroll
    for (int ct = 0; ct < 2; ct++)
      #pragma unroll
      for (int n2 = 0; n2 < 4; n2++)
        acc3[ct][n2] = {0.f, 0.f, 0.f, 0.f};
    bf16x8 afA[2][2];
    #pragma unroll
    for (int ct = 0; ct < 2; ct++)
      #pragma unroll
      for (int kk = 0; kk < 2; kk++)
        afA[ct][kk] = *(const bf16x8*)(Abf + (ct*16 + r16)*64 + kk*32 + g*8);
    #pragma unroll
    for (int kk = 0; kk < 2; kk++) {
      #pragma unroll
      for (int n2 = 0; n2 < 4; n2++) {
        int h = h0 + n2*16 + r16;
        bf16x8 b8 = *(const bf16x8*)(smem + 16384 + b_w*16384 + h*128 +
                                     ((kk*64 + g*16) ^ ((h&7)<<4)));
        #pragma unroll
        for (int ct = 0; ct < 2; ct++)
          acc3[ct][n2] = __builtin_amdgcn_mfma_f32_16x16x32_bf16(afA[ct][kk], b8, acc3[ct][n2], 0, 0, 0);
      }
    }
    #pragma unroll
    for (int n2 = 0; n2 < 4; n2++) {
      int hg2 = col0 + h0 + n2*16 + r16;
      #pragma unroll
      for (int ct = 0; ct < 2; ct++) {
        if (ct == 1 && g >= 2) continue;    // c >= 24 pad rows
        #pragma unroll
        for (int r = 0; r < 4; r++) {
          int c = ct*16 + g*4 + r;
          outp[((size_t)(bglob*NC + c))*DIM + hg2] = __float2bfloat16(acc3[ct][n2][r]);
        }
      }
    }
  }
}

// ---- k_next: A=Hw, dual-B GEMM. N-half 0 (W2T): y1/traj/y0/y0bf.
//      N-half 1 (W21T): C += sc*acc + sc*sumw*bb ; H1 = bf16(tanh(C')) ----
__global__ __launch_bounds__(256, 3) void k_next(const bf16* __restrict__ A,
    const bf16* __restrict__ W2T, const bf16* __restrict__ W21T,
    const float* __restrict__ b2, const float* __restrict__ bb,
    float* __restrict__ y0, bf16* __restrict__ y0bf, float* __restrict__ C,
    bf16* __restrict__ H1, const float* __restrict__ scales, int t,
    float* __restrict__ traj) {
  __shared__ bf16 sA[2][128*64];
  __shared__ bf16 sB[2][64*64];
  int tid = threadIdx.x;
  int lane = tid & 63, wid = tid >> 6;
  int q8 = gridDim.x >> 3;                    // 4
  int tl = (blockIdx.x & 7)*q8 + (blockIdx.x >> 3);
  int bm = tl >> 4, bn = tl & 15;
  int half = bn >> 3;                         // 0: W2T, 1: W21T
  int row0 = bm*128, col0 = (bn & 7)*64;
  const bf16* BT = half ? W21T : W2T;
  int wr = wid >> 1, wc = wid & 1;
  int r16 = lane & 15, g = lane >> 4;

  f32x4 acc[4][2];
  #pragma unroll
  for (int m = 0; m < 4; m++)
    #pragma unroll
    for (int n = 0; n < 2; n++)
      acc[m][n] = {0.f, 0.f, 0.f, 0.f};

  auto stage = [&](int buf, int k0) {
    #pragma unroll
    for (int j = 0; j < 4; j++) {
      int cid = wid*64 + lane + j*256;
      int r = cid >> 3;
      int c = (cid & 7) ^ (r & 7);
      gld_lds16(A + (size_t)(row0 + r)*DIM + k0 + c*8,
                (char*)&sA[buf][0] + wid*1024 + j*4096);
    }
    #pragma unroll
    for (int j = 0; j < 2; j++) {
      int cid = wid*64 + lane + j*256;
      int r = cid >> 3;
      int c = (cid & 7) ^ (r & 7);
      gld_lds16(BT + (size_t)(col0 + r)*DIM + k0 + c*8,
                (char*)&sB[buf][0] + wid*1024 + j*4096);
    }
  };

  stage(0, 0);
  int cur = 0;
  for (int k0 = 0; k0 < DIM; k0 += 64) {
    if (k0 + 64 < DIM) {
      stage(cur ^ 1, k0 + 64);
      asm volatile("s_waitcnt vmcnt(6)" ::: "memory");
    } else {
      asm volatile("s_waitcnt vmcnt(0)" ::: "memory");
    }
    __builtin_amdgcn_s_barrier();
    #pragma unroll
    for (int kk = 0; kk < 2; kk++) {
      bf16x8 af[4], bfr[2];
      #pragma unroll
      for (int m = 0; m < 4; m++) {
        int r = wr*64 + m*16 + r16;
        af[m] = *(const bf16x8*)(&sA[cur][0] + r*64 + (((kk*4+g) ^ (r&7))*8));
      }
      #pragma unroll
      for (int n = 0; n < 2; n++) {
        int r = wc*32 + n*16 + r16;
        bfr[n] = *(const bf16x8*)(&sB[cur][0] + r*64 + (((kk*4+g) ^ (r&7))*8));
      }
      #pragma unroll
      for (int m = 0; m < 4; m++)
        #pragma unroll
        for (int n = 0; n < 2; n++)
          acc[m][n] = __builtin_amdgcn_mfma_f32_16x16x32_bf16(af[m], bfr[n], acc[m][n], 0, 0, 0);
    }
    __builtin_amdgcn_s_barrier();
    cur ^= 1;
  }

  float sc = scales[t];
  float sumw = scales[6];
  #pragma unroll
  for (int m = 0; m < 4; m++) {
    int rowb = row0 + wr*64 + m*16 + g*4;
    #pragma unroll
    for (int n = 0; n < 2; n++) {
      int col = col0 + wc*32 + n*16 + r16;
      #pragma unroll
      for (int r = 0; r < 4; r++) {
        size_t idx = (size_t)(rowb + r)*DIM + col;
        if (half == 0) {
          float bv = sumw * b2[col];
          float y1 = fmaf(sc, acc[m][n][r] + bv, y0[idx]);
          y0[idx] = y1;
          y0bf[idx] = __float2bfloat16(y1);
          traj[idx] = y1;
        } else {
          float cb = sc * sumw * bb[col];
          float cnew = fmaf(sc, acc[m][n][r], C[idx] + cb);
          C[idx] = cnew;
          H1[idx] = __float2bfloat16(fast_tanh(cnew));
        }
      }
    }
  }
}

extern "C" void kernel_launch(void* const* d_in, const int* in_sizes, int n_in,
                              void* d_out, int out_size, void* d_ws, size_t ws_size,
                              hipStream_t stream) {
  const float* y_init = (const float*)d_in[0];
  const float* t_span = (const float*)d_in[1];
  const float* W1 = (const float*)d_in[2];
  const float* b1 = (const float*)d_in[3];
  const float* W2 = (const float*)d_in[4];
  const float* b2 = (const float*)d_in[5];
  float* out = (float*)d_out;

  char* ws = (char*)d_ws;
  size_t off = 0;
  auto carve = [&](size_t bytes) {
    void* p = ws + off; off += (bytes + 255) & ~(size_t)255; return p;
  };
  bf16*  Tbf    = (bf16*) carve((size_t)48*32*2);
  bf16*  Abf    = (bf16*) carve((size_t)32*64*2);
  float* a1     = (float*)carve(NC*4);
  float* rs     = (float*)carve(NP*4);
  float* wv     = (float*)carve(NP*4);
  float* bb     = (float*)carve(DIM*4);
  float* scales = (float*)carve(8*4);
  float* zbias  = (float*)carve(DIM*4);
  float* y0     = (float*)carve((size_t)NELEM*4);
  float* C      = (float*)carve((size_t)NELEM*4);
  bf16*  y0bf   = (bf16*) carve((size_t)NELEM*2);
  bf16*  H1     = (bf16*) carve((size_t)NELEM*2);
  bf16*  Hw     = (bf16*) carve((size_t)NELEM*2);
  bf16*  W1T    = (bf16*) carve((size_t)DIM*DIM*2);
  bf16*  W2T    = (bf16*) carve((size_t)DIM*DIM*2);
  bf16*  W2bf   = (bf16*) carve((size_t)DIM*DIM*2);
  bf16*  W21T   = (bf16*) carve((size_t)DIM*DIM*2);
  bf16*  Pa     = (bf16*) carve((size_t)PROWS*DIM*2);
  bf16*  Pb     = (bf16*) carve((size_t)PROWS*DIM*2);

  k_setup<<<1, 64, 0, stream>>>(t_span, Tbf, Abf, a1, rs, wv, scales, zbias, out);
  k_wt<<<(DIM*DIM)/256, 256, 0, stream>>>(W1, W2, W1T, W2T, W2bf);
  k_bb<<<2, 256, 0, stream>>>(W1, b2, bb);
  // W21T[h][i] = (W2.W1)[i][h]  (one-time 512^3 GEMM)
  k_gemm<1><<<32, 256, 0, stream>>>(W1T, W2bf, zbias, W21T, nullptr);
  k_init<<<NELEM/256, 256, 0, stream>>>(y_init, y0, y0bf, out + 7);
  // C = y0.W1 + b1 (f32), H1 = tanh(C)  -- interval 0; k_next updates afterwards
  k_gemm<2><<<16, 256, 0, stream>>>(y0bf, W1T, b1, H1, C);

  const int GRID = (BATCH/2)*(DIM/128);   // 128*4 = 512 = 2/CU

  for (int t = 0; t < NI; t++) {
    // Picard iter 2 (iter 1 folded via rank-1 G24): H1 -> Pa
    k_iter<0><<<GRID, 256, 0, stream>>>(nullptr, H1, W21T, C, bb, Tbf, Abf,
                                        a1, rs, wv, scales, t, Pa);
    // iters 3,4: P -> P'
    k_iter<1><<<GRID, 256, 0, stream>>>(Pa, nullptr, W21T, C, bb, Tbf, Abf,
                                        a1, rs, wv, scales, t, Pb);
    k_iter<1><<<GRID, 256, 0, stream>>>(Pb, nullptr, W21T, C, bb, Tbf, Abf,
                                        a1, rs, wv, scales, t, Pa);
    // iter 5: P -> Hw
    k_iter<2><<<GRID, 256, 0, stream>>>(Pa, nullptr, W21T, C, bb, Tbf, Abf,
                                        a1, rs, wv, scales, t, Hw);
    // y1 (traj/y0) and next interval's C/H1 in one dual-B GEMM
    k_next<<<32, 256, 0, stream>>>(Hw, W2T, W21T, b2, bb, y0, y0bf, C, H1,
                                   scales, t, out + 7 + (size_t)(t+1)*NELEM);
  }
}

// Round 12
// 425.732 us; speedup vs baseline: 1.0009x; 1.0009x over previous
//
#include <hip/hip_runtime.h>
#include <hip/hip_bf16.h>
#include <math.h>

#define NC 24
#define NP 48
#define NI 6
#define BATCH 256
#define DIM 512
#define NELEM (BATCH*DIM)     // 131072
#define PROWS (BATCH*NC)      // 6144

typedef __bf16 bf16x8 __attribute__((ext_vector_type(8)));
typedef unsigned short u16x8 __attribute__((ext_vector_type(8)));
typedef float f32x4 __attribute__((ext_vector_type(4)));
using bf16 = __hip_bfloat16;

struct bq8 { __hip_bfloat162 a, b; };   // 8-byte LDS write

__device__ __forceinline__ void gld_lds16(const void* g, void* l) {
  __builtin_amdgcn_global_load_lds(
      (const __attribute__((address_space(1))) void*)g,
      (__attribute__((address_space(3))) void*)l, 16, 0, 0);
}

__device__ __forceinline__ float fast_tanh(float x) {
  float u = __expf(2.0f * x);
  float r = __builtin_amdgcn_rcpf(u + 1.0f);
  return __builtin_fmaf(-2.0f, r, 1.0f);
}

__device__ __forceinline__ float bfu(unsigned short u) {
  union { unsigned int i; float f; } v; v.i = ((unsigned)u) << 16; return v.f;
}

// ---- constants: Tbf[48][32] (T^T, c-pad), Abf[32][64] (A24, pads), a1[24],
//      rs[p] = sum_q M[p][q], wv, scales(+sumw), zbias ----
__global__ void k_setup(const float* __restrict__ t_span, bf16* __restrict__ Tbf,
                        bf16* __restrict__ Abf, float* __restrict__ a1,
                        float* __restrict__ rs, float* __restrict__ wv,
                        float* __restrict__ scales, float* __restrict__ zbias,
                        float* __restrict__ out) {
  __shared__ double Tsh[NC][NP];
  __shared__ double Ashd[NC][NP];
  __shared__ double a1sh[NC];
  __shared__ double wsh[NP];
  int tid = threadIdx.x;   // 64
  for (int idx = tid; idx < NC*NP; idx += 64) {
    int c = idx / NP, p = idx % NP;
    Tsh[c][p] = cos((double)c * (M_PI * ((double)p + 0.5) / NP));
  }
  for (int idx = tid; idx < 32*64; idx += 64) Abf[idx] = __float2bfloat16(0.f);
  for (int idx = tid; idx < 48*32; idx += 64) Tbf[idx] = __float2bfloat16(0.f);
  __syncthreads();
  if (tid < NP) {
    int q = tid;
    double V[NC], K[NC];
    for (int c = 0; c < NC; c++) V[c] = (2.0/NP) * Tsh[c][q];
    V[0] *= 0.5;
    double s = 0.0;
    for (int n = 1; n < NC; n++) {
      double hi = (n+1 < NC) ? V[n+1] : 0.0;
      K[n] = (V[n-1] - hi) / (2.0*n);
      s += (n & 1) ? -K[n] : K[n];
    }
    K[0] = -s;
    double wsum = 0.0;
    for (int c = 0; c < NC; c++) wsum += K[c];
    wv[q] = (float)wsum;
    wsh[q] = wsum;
    for (int c = 0; c < NC; c++) {
      Ashd[c][q] = K[c];
      Abf[c*64 + q] = __float2bfloat16((float)K[c]);
    }
  }
  __syncthreads();
  if (tid < NC) {
    double s = 0.0;
    for (int q = 0; q < NP; q++) s += Ashd[tid][q];
    a1sh[tid] = s;
    a1[tid] = (float)s;
  }
  __syncthreads();
  if (tid < NP) {
    int p = tid;
    double r = 0.0;
    for (int c = 0; c < NC; c++) r += Tsh[c][p] * a1sh[c];
    rs[p] = (float)r;
    for (int c = 0; c < NC; c++) Tbf[p*32 + c] = __float2bfloat16((float)Tsh[c][p]);
  }
  if (tid == 0) {
    double s = 0.0;
    for (int q = 0; q < NP; q++) s += wsh[q];
    scales[6] = (float)s;                        // sumw
  }
  for (int idx = tid; idx < DIM; idx += 64) zbias[idx] = 0.f;
  if (tid < NI) scales[tid] = 0.5f*(t_span[tid+1]-t_span[tid]);
  if (tid < NI+1) out[tid] = t_span[tid];
}

// ---- weights -> bf16: W1T[h][d], W2T[d][h], W2bf[h][d] ----
__global__ void k_wt(const float* __restrict__ W1, const float* __restrict__ W2,
                     bf16* __restrict__ W1T, bf16* __restrict__ W2T,
                     bf16* __restrict__ W2bf) {
  int idx = blockIdx.x*256 + threadIdx.x;
  int k = idx >> 9, n = idx & 511;
  W1T[n*DIM + k] = __float2bfloat16(W1[idx]);
  W2T[n*DIM + k] = __float2bfloat16(W2[idx]);
  W2bf[idx]      = __float2bfloat16(W2[idx]);
}

// ---- bb[h] = sum_d b2[d] * W1[d][h] ----
__global__ void k_bb(const float* __restrict__ W1, const float* __restrict__ b2,
                     float* __restrict__ bb) {
  int h = blockIdx.x*256 + threadIdx.x;
  float s = 0.f;
  for (int d = 0; d < DIM; d++) s = fmaf(b2[d], W1[d*DIM + h], s);
  bb[h] = s;
}

// ---- init: y0, y0bf, traj[0] ----
__global__ void k_init(const float* __restrict__ y_init, float* __restrict__ y0,
                       bf16* __restrict__ y0bf, float* __restrict__ traj0) {
  int i = blockIdx.x*256 + threadIdx.x;
  float v = y_init[i];
  y0[i] = v; traj0[i] = v;
  y0bf[i] = __float2bfloat16(v);
}

// ---- generic bf16 MFMA GEMM: tile 128x64, BK=64, dbuf, counted vmcnt ----
// EPI 1: outb = bf16(acc + bias)
// EPI 2: outf = acc + bias (f32, =C); outb = bf16(tanh(C)) (=H1)
template<int EPI>
__global__ __launch_bounds__(256, 3) void k_gemm(const bf16* __restrict__ A,
    const bf16* __restrict__ BT, const float* __restrict__ bias,
    bf16* __restrict__ outb, float* __restrict__ outf) {
  __shared__ bf16 sA[2][128*64];
  __shared__ bf16 sB[2][64*64];
  int tid = threadIdx.x;
  int lane = tid & 63, wid = tid >> 6;
  int q8 = gridDim.x >> 3;
  int tl = (blockIdx.x & 7)*q8 + (blockIdx.x >> 3);
  int bm = tl >> 3, bn = tl & 7;
  int row0 = bm*128, col0 = bn*64;
  int wr = wid >> 1, wc = wid & 1;
  int r16 = lane & 15, g = lane >> 4;

  f32x4 acc[4][2];
  #pragma unroll
  for (int m = 0; m < 4; m++)
    #pragma unroll
    for (int n = 0; n < 2; n++)
      acc[m][n] = {0.f, 0.f, 0.f, 0.f};

  auto stage = [&](int buf, int k0) {
    #pragma unroll
    for (int j = 0; j < 4; j++) {
      int cid = wid*64 + lane + j*256;
      int r = cid >> 3;
      int c = (cid & 7) ^ (r & 7);
      gld_lds16(A + (size_t)(row0 + r)*DIM + k0 + c*8,
                (char*)&sA[buf][0] + wid*1024 + j*4096);
    }
    #pragma unroll
    for (int j = 0; j < 2; j++) {
      int cid = wid*64 + lane + j*256;
      int r = cid >> 3;
      int c = (cid & 7) ^ (r & 7);
      gld_lds16(BT + (size_t)(col0 + r)*DIM + k0 + c*8,
                (char*)&sB[buf][0] + wid*1024 + j*4096);
    }
  };

  stage(0, 0);
  int cur = 0;
  for (int k0 = 0; k0 < DIM; k0 += 64) {
    if (k0 + 64 < DIM) {
      stage(cur ^ 1, k0 + 64);
      asm volatile("s_waitcnt vmcnt(6)" ::: "memory");
    } else {
      asm volatile("s_waitcnt vmcnt(0)" ::: "memory");
    }
    __builtin_amdgcn_s_barrier();
    #pragma unroll
    for (int kk = 0; kk < 2; kk++) {
      bf16x8 af[4], bfr[2];
      #pragma unroll
      for (int m = 0; m < 4; m++) {
        int r = wr*64 + m*16 + r16;
        af[m] = *(const bf16x8*)(&sA[cur][0] + r*64 + (((kk*4+g) ^ (r&7))*8));
      }
      #pragma unroll
      for (int n = 0; n < 2; n++) {
        int r = wc*32 + n*16 + r16;
        bfr[n] = *(const bf16x8*)(&sB[cur][0] + r*64 + (((kk*4+g) ^ (r&7))*8));
      }
      #pragma unroll
      for (int m = 0; m < 4; m++)
        #pragma unroll
        for (int n = 0; n < 2; n++)
          acc[m][n] = __builtin_amdgcn_mfma_f32_16x16x32_bf16(af[m], bfr[n], acc[m][n], 0, 0, 0);
    }
    __builtin_amdgcn_s_barrier();
    cur ^= 1;
  }

  #pragma unroll
  for (int m = 0; m < 4; m++) {
    int rowb = row0 + wr*64 + m*16 + g*4;
    #pragma unroll
    for (int n = 0; n < 2; n++) {
      int col = col0 + wc*32 + n*16 + r16;
      float bv = bias[col];
      #pragma unroll
      for (int r = 0; r < 4; r++) {
        float v = acc[m][n][r] + bv;
        size_t idx = (size_t)(rowb + r)*DIM + col;
        if constexpr (EPI == 1) {
          outb[idx] = __float2bfloat16(v);
        } else {
          outf[idx] = v;
          outb[idx] = __float2bfloat16(fast_tanh(v));
        }
      }
    }
  }
}

// ---- k_iter v2: one Picard iteration, 24-coeff space. Tile: 4 b's x 128 h,
// 512 threads (8 waves), grid 256 = 1 block/CU. Halves staged B-traffic vs R10.
// MODE 0 (FIRST): G24 = a1 (x) (H1.W21) per-thread dot; phases B,C -> P'
// MODE 1 (MID):   A: G24 = P.W21 (96x128 MFMA, 2-buf); B: Z = C+sc(T.G24+rs*bb);
//                 C: P' = A24.tanh(Z)
// MODE 2 (FIN):   A,B -> Hw = sum_p wv[p]*tanh(Z[p])
// Dynamic LDS 98304: staging sA[2][96x64] @0 (24K), sB[2][128x64] @24576 (32K)
//   overlay: sGT[b=4][h=128][c=32] @0 (32K, slot^((h>>1)&3));
//            sHT[b=4][h=128][p=64] @32768 (64K, ^((h&7)<<4)); sH1 @32768 (MODE0)
template<int MODE>
__global__ __launch_bounds__(512, 2) void k_iter(
    const bf16* __restrict__ Pin, const bf16* __restrict__ H1,
    const bf16* __restrict__ W21T, const float* __restrict__ Cg,
    const float* __restrict__ bbg, const bf16* __restrict__ Tbf,
    const bf16* __restrict__ Abf, const float* __restrict__ a1,
    const float* __restrict__ rsg, const float* __restrict__ wvg,
    const float* __restrict__ scales, int t, bf16* __restrict__ outp) {
  extern __shared__ char smem[];
  int tid = threadIdx.x;                   // 0..511
  int lane = tid & 63, wid = tid >> 6;     // wid 0..7
  int r16 = lane & 15, g = lane >> 4;
  int q8 = gridDim.x >> 3;                 // 32
  int tl = (blockIdx.x & 7)*q8 + (blockIdx.x >> 3);
  int bm = tl >> 2, bn = tl & 3;           // bm 0..63
  int col0 = bn*128;
  int bglob0 = bm*4;

  if constexpr (MODE != 0) {
    // ---- Phase A: G24 = P.W21, rows [bm*96,+96), cols [col0,+128) ----
    int row0 = bm*96;
    int wr = wid >> 2, wc = wid & 3;       // wave tile: 48 rows x 32 cols
    f32x4 acc[3][2];
    #pragma unroll
    for (int m = 0; m < 3; m++)
      #pragma unroll
      for (int n = 0; n < 2; n++)
        acc[m][n] = {0.f, 0.f, 0.f, 0.f};

    auto stage = [&](int buf, int k0) {
      // A: 768 chunks (96 rows x 8); pass0 = 512 (all), pass1 = 256 (wid<4)
      {
        int cid = wid*64 + lane;
        int r = cid >> 3, cc = (cid & 7) ^ (r & 7);
        gld_lds16(Pin + (size_t)(row0 + r)*DIM + k0 + cc*8,
                  smem + buf*12288 + wid*1024);
      }
      if (wid < 4) {
        int cid = 512 + wid*64 + lane;
        int r = cid >> 3, cc = (cid & 7) ^ (r & 7);
        gld_lds16(Pin + (size_t)(row0 + r)*DIM + k0 + cc*8,
                  smem + buf*12288 + 8192 + wid*1024);
      }
      // B: 1024 chunks (128 rows x 8) = 2 x 512
      #pragma unroll
      for (int j = 0; j < 2; j++) {
        int cid = j*512 + wid*64 + lane;
        int r = cid >> 3, cc = (cid & 7) ^ (r & 7);
        gld_lds16(W21T + (size_t)(col0 + r)*DIM + k0 + cc*8,
                  smem + 24576 + buf*16384 + j*8192 + wid*1024);
      }
    };

    stage(0, 0);
    int cur = 0;
    for (int ks = 0; ks < 8; ks++) {
      if (ks < 7) {
        stage(cur ^ 1, (ks+1)*64);
        asm volatile("s_waitcnt vmcnt(3)" ::: "memory");  // current tile landed
      } else {
        asm volatile("s_waitcnt vmcnt(0)" ::: "memory");
      }
      __builtin_amdgcn_s_barrier();
      const char* sAc = smem + cur*12288;
      const char* sBc = smem + 24576 + cur*16384;
      #pragma unroll
      for (int kk = 0; kk < 2; kk++) {
        bf16x8 af[3], bfr[2];
        #pragma unroll
        for (int m = 0; m < 3; m++) {
          int r = wr*48 + m*16 + r16;
          af[m] = *(const bf16x8*)(sAc + r*128 + ((kk*4+g) ^ (r&7))*16);
        }
        #pragma unroll
        for (int n = 0; n < 2; n++) {
          int r = wc*32 + n*16 + r16;
          bfr[n] = *(const bf16x8*)(sBc + r*128 + ((kk*4+g) ^ (r&7))*16);
        }
        #pragma unroll
        for (int m = 0; m < 3; m++)
          #pragma unroll
          for (int n = 0; n < 2; n++)
            acc[m][n] = __builtin_amdgcn_mfma_f32_16x16x32_bf16(af[m], bfr[n], acc[m][n], 0, 0, 0);
      }
      __builtin_amdgcn_s_barrier();
      cur ^= 1;
    }

    // write G24 -> sGT[b][h][c] (rows of 64B, slot swizzle)
    #pragma unroll
    for (int m = 0; m < 3; m++) {
      int rowf = wr*48 + m*16 + g*4;        // multiple of 4; never crosses b (24 | rows)
      int b_loc = rowf / 24;
      int c0 = rowf - b_loc*24;
      int slot = c0 >> 3;
      int inb  = (c0*2) & 15;
      #pragma unroll
      for (int n = 0; n < 2; n++) {
        int h = wc*32 + n*16 + r16;
        char* ad = smem + b_loc*8192 + h*64 + (((slot ^ ((h>>1)&3)) << 4) | inb);
        bq8 v;
        v.a = __hip_bfloat162{__float2bfloat16(acc[m][n][0]), __float2bfloat16(acc[m][n][1])};
        v.b = __hip_bfloat162{__float2bfloat16(acc[m][n][2]), __float2bfloat16(acc[m][n][3])};
        *(bq8*)ad = v;
      }
    }
  } else {
    // ---- FIRST: sH1 <- 4 b's of H1; per-thread g1 = H1[b].W21[:,h]; sGT = a1 (x) g1 ----
    bf16* sH1 = (bf16*)(smem + 32768);
    #pragma unroll
    for (int j = 0; j < 4; j++) {
      int e = j*512 + tid;                  // [0,2048)
      int b = e >> 9, k = e & 511;
      sH1[e] = H1[(size_t)(bglob0 + b)*DIM + k];
    }
    __syncthreads();
    int b = tid >> 7, hl = tid & 127;       // 4 b x 128 h = 512 threads
    int hg = col0 + hl;
    const bf16* wrow = W21T + (size_t)hg*DIM;
    const bf16* hrow = sH1 + b*512;
    float g1 = 0.f;
    for (int ks = 0; ks < 64; ks++) {
      u16x8 w8 = *(const u16x8*)(wrow + ks*8);
      u16x8 h8 = *(const u16x8*)(hrow + ks*8);
      #pragma unroll
      for (int i = 0; i < 8; i++)
        g1 = fmaf(bfu(h8[i]), bfu(w8[i]), g1);
    }
    __syncthreads();
    int rot = ((hl>>1)&3) << 4;
    #pragma unroll
    for (int c = 0; c < NC; c++) {
      int lb = c*2;
      char* ad = smem + b*8192 + hl*64 + ((( (lb>>4) << 4) ^ rot) | (lb & 15));
      *(bf16*)ad = __float2bfloat16(a1[c]*g1);
    }
  }

  // zero sGT pad slot (c 24..31); 512 threads cover 4 b x 128 h
  {
    int bz = tid >> 7, hz = tid & 127;
    *(f32x4*)(smem + bz*8192 + hz*64 + ((3 ^ ((hz>>1)&3)) << 4)) = f32x4{0.f,0.f,0.f,0.f};
  }
  __syncthreads();

  // ---- Phase B: Z = C + sc*(T48.G24 + rs*bb); tanh ----
  int b_w = wid >> 1;                      // 0..3
  int h0 = (wid & 1) << 6;
  int bglob = bglob0 + b_w;
  float sc = scales[t];

  f32x4 acc2[3][4];
  #pragma unroll
  for (int pt = 0; pt < 3; pt++)
    #pragma unroll
    for (int n2 = 0; n2 < 4; n2++)
      acc2[pt][n2] = {0.f, 0.f, 0.f, 0.f};
  {
    bf16x8 afT[3];
    #pragma unroll
    for (int pt = 0; pt < 3; pt++)
      afT[pt] = *(const bf16x8*)(Tbf + (pt*16 + r16)*32 + g*8);
    #pragma unroll
    for (int n2 = 0; n2 < 4; n2++) {
      int h = h0 + n2*16 + r16;
      bf16x8 b8 = *(const bf16x8*)(smem + b_w*8192 + h*64 + ((g ^ ((h>>1)&3)) << 4));
      #pragma unroll
      for (int pt = 0; pt < 3; pt++)
        acc2[pt][n2] = __builtin_amdgcn_mfma_f32_16x16x32_bf16(afT[pt], b8, acc2[pt][n2], 0, 0, 0);
    }
  }

  float rsv[12];
  #pragma unroll
  for (int pt = 0; pt < 3; pt++)
    #pragma unroll
    for (int r = 0; r < 4; r++)
      rsv[pt*4+r] = rsg[pt*16 + g*4 + r];

  if constexpr (MODE == 2) {
    // FIN: Hw = sum_p wv[p]*tanh(Z[p])
    float wvv[12];
    #pragma unroll
    for (int pt = 0; pt < 3; pt++)
      #pragma unroll
      for (int r = 0; r < 4; r++)
        wvv[pt*4+r] = wvg[pt*16 + g*4 + r];
    #pragma unroll
    for (int n2 = 0; n2 < 4; n2++) {
      int hg2 = col0 + h0 + n2*16 + r16;
      float cv = Cg[(size_t)bglob*DIM + hg2];
      float bbv = bbg[hg2];
      float hw = 0.f;
      #pragma unroll
      for (int pt = 0; pt < 3; pt++)
        #pragma unroll
        for (int r = 0; r < 4; r++) {
          float z = fmaf(sc, fmaf(rsv[pt*4+r], bbv, acc2[pt][n2][r]), cv);
          hw = fmaf(wvv[pt*4+r], fast_tanh(z), hw);
        }
      hw += __shfl_xor(hw, 16);
      hw += __shfl_xor(hw, 32);
      if (g == 0)
        outp[(size_t)bglob*DIM + hg2] = __float2bfloat16(hw);
    }
    return;
  } else {
    // tanh -> sHT[b][h][p]
    #pragma unroll
    for (int n2 = 0; n2 < 4; n2++) {
      int h = h0 + n2*16 + r16;
      int hg2 = col0 + h;
      float cv = Cg[(size_t)bglob*DIM + hg2];
      float bbv = bbg[hg2];
      #pragma unroll
      for (int pt = 0; pt < 3; pt++) {
        int p0 = pt*16 + g*4;
        float th[4];
        #pragma unroll
        for (int r = 0; r < 4; r++) {
          float z = fmaf(sc, fmaf(rsv[pt*4+r], bbv, acc2[pt][n2][r]), cv);
          th[r] = fast_tanh(z);
        }
        char* ad = smem + 32768 + b_w*16384 + h*128 + ((p0*2) ^ ((h&7)<<4));
        bq8 v;
        v.a = __hip_bfloat162{__float2bfloat16(th[0]), __float2bfloat16(th[1])};
        v.b = __hip_bfloat162{__float2bfloat16(th[2]), __float2bfloat16(th[3])};
        *(bq8*)ad = v;
      }
    }
    // zero sHT pad p 48..63; 512 threads cover 4 b x 128 h
    {
      int bz = tid >> 7, hz = tid & 127;
      char* base = smem + 32768 + bz*16384 + hz*128;
      *(f32x4*)(base + (96  ^ ((hz&7)<<4))) = f32x4{0.f,0.f,0.f,0.f};
      *(f32x4*)(base + (112 ^ ((hz&7)<<4))) = f32x4{0.f,0.f,0.f,0.f};
    }
    __syncthreads();

    // ---- Phase C: P' = A24.tanh(Z) ----
    f32x4 acc3[2][4];
    #pragma unroll
    for (int ct = 0; ct < 2; ct++)
      #pragma unroll
      for (int n2 = 0; n2 < 4; n2++)
        acc3[ct][n2] = {0.f, 0.f, 0.f, 0.f};
    bf16x8 afA[2][2];
    #pragma unroll
    for (int ct = 0; ct < 2; ct++)
      #pragma unroll
      for (int kk = 0; kk < 2; kk++)
        afA[ct][kk] = *(const bf16x8*)(Abf + (ct*16 + r16)*64 + kk*32 + g*8);
    #pragma unroll
    for (int kk = 0; kk < 2; kk++) {
      #pragma unroll
      for (int n2 = 0; n2 < 4; n2++) {
        int h = h0 + n2*16 + r16;
        bf16x8 b8 = *(const bf16x8*)(smem + 32768 + b_w*16384 + h*128 +
                                     ((kk*64 + g*16) ^ ((h&7)<<4)));
        #pragma unroll
        for (int ct = 0; ct < 2; ct++)
          acc3[ct][n2] = __builtin_amdgcn_mfma_f32_16x16x32_bf16(afA[ct][kk], b8, acc3[ct][n2], 0, 0, 0);
      }
    }
    #pragma unroll
    for (int n2 = 0; n2 < 4; n2++) {
      int hg2 = col0 + h0 + n2*16 + r16;
      #pragma unroll
      for (int ct = 0; ct < 2; ct++) {
        if (ct == 1 && g >= 2) continue;    // c >= 24 pad rows
        #pragma unroll
        for (int r = 0; r < 4; r++) {
          int c = ct*16 + g*4 + r;
          outp[((size_t)(bglob*NC + c))*DIM + hg2] = __float2bfloat16(acc3[ct][n2][r]);
        }
      }
    }
  }
}

// ---- k_next: A=Hw, dual-B GEMM. N-half 0 (W2T): y1/traj/y0/y0bf.
//      N-half 1 (W21T): C += sc*acc + sc*sumw*bb ; H1 = bf16(tanh(C')) ----
__global__ __launch_bounds__(256, 3) void k_next(const bf16* __restrict__ A,
    const bf16* __restrict__ W2T, const bf16* __restrict__ W21T,
    const float* __restrict__ b2, const float* __restrict__ bb,
    float* __restrict__ y0, bf16* __restrict__ y0bf, float* __restrict__ C,
    bf16* __restrict__ H1, const float* __restrict__ scales, int t,
    float* __restrict__ traj) {
  __shared__ bf16 sA[2][128*64];
  __shared__ bf16 sB[2][64*64];
  int tid = threadIdx.x;
  int lane = tid & 63, wid = tid >> 6;
  int q8 = gridDim.x >> 3;                    // 4
  int tl = (blockIdx.x & 7)*q8 + (blockIdx.x >> 3);
  int bm = tl >> 4, bn = tl & 15;
  int half = bn >> 3;                         // 0: W2T, 1: W21T
  int row0 = bm*128, col0 = (bn & 7)*64;
  const bf16* BT = half ? W21T : W2T;
  int wr = wid >> 1, wc = wid & 1;
  int r16 = lane & 15, g = lane >> 4;

  f32x4 acc[4][2];
  #pragma unroll
  for (int m = 0; m < 4; m++)
    #pragma unroll
    for (int n = 0; n < 2; n++)
      acc[m][n] = {0.f, 0.f, 0.f, 0.f};

  auto stage = [&](int buf, int k0) {
    #pragma unroll
    for (int j = 0; j < 4; j++) {
      int cid = wid*64 + lane + j*256;
      int r = cid >> 3;
      int c = (cid & 7) ^ (r & 7);
      gld_lds16(A + (size_t)(row0 + r)*DIM + k0 + c*8,
                (char*)&sA[buf][0] + wid*1024 + j*4096);
    }
    #pragma unroll
    for (int j = 0; j < 2; j++) {
      int cid = wid*64 + lane + j*256;
      int r = cid >> 3;
      int c = (cid & 7) ^ (r & 7);
      gld_lds16(BT + (size_t)(col0 + r)*DIM + k0 + c*8,
                (char*)&sB[buf][0] + wid*1024 + j*4096);
    }
  };

  stage(0, 0);
  int cur = 0;
  for (int k0 = 0; k0 < DIM; k0 += 64) {
    if (k0 + 64 < DIM) {
      stage(cur ^ 1, k0 + 64);
      asm volatile("s_waitcnt vmcnt(6)" ::: "memory");
    } else {
      asm volatile("s_waitcnt vmcnt(0)" ::: "memory");
    }
    __builtin_amdgcn_s_barrier();
    #pragma unroll
    for (int kk = 0; kk < 2; kk++) {
      bf16x8 af[4], bfr[2];
      #pragma unroll
      for (int m = 0; m < 4; m++) {
        int r = wr*64 + m*16 + r16;
        af[m] = *(const bf16x8*)(&sA[cur][0] + r*64 + (((kk*4+g) ^ (r&7))*8));
      }
      #pragma unroll
      for (int n = 0; n < 2; n++) {
        int r = wc*32 + n*16 + r16;
        bfr[n] = *(const bf16x8*)(&sB[cur][0] + r*64 + (((kk*4+g) ^ (r&7))*8));
      }
      #pragma unroll
      for (int m = 0; m < 4; m++)
        #pragma unroll
        for (int n = 0; n < 2; n++)
          acc[m][n] = __builtin_amdgcn_mfma_f32_16x16x32_bf16(af[m], bfr[n], acc[m][n], 0, 0, 0);
    }
    __builtin_amdgcn_s_barrier();
    cur ^= 1;
  }

  float sc = scales[t];
  float sumw = scales[6];
  #pragma unroll
  for (int m = 0; m < 4; m++) {
    int rowb = row0 + wr*64 + m*16 + g*4;
    #pragma unroll
    for (int n = 0; n < 2; n++) {
      int col = col0 + wc*32 + n*16 + r16;
      #pragma unroll
      for (int r = 0; r < 4; r++) {
        size_t idx = (size_t)(rowb + r)*DIM + col;
        if (half == 0) {
          float bv = sumw * b2[col];
          float y1 = fmaf(sc, acc[m][n][r] + bv, y0[idx]);
          y0[idx] = y1;
          y0bf[idx] = __float2bfloat16(y1);
          traj[idx] = y1;
        } else {
          float cb = sc * sumw * bb[col];
          float cnew = fmaf(sc, acc[m][n][r], C[idx] + cb);
          C[idx] = cnew;
          H1[idx] = __float2bfloat16(fast_tanh(cnew));
        }
      }
    }
  }
}

extern "C" void kernel_launch(void* const* d_in, const int* in_sizes, int n_in,
                              void* d_out, int out_size, void* d_ws, size_t ws_size,
                              hipStream_t stream) {
  const float* y_init = (const float*)d_in[0];
  const float* t_span = (const float*)d_in[1];
  const float* W1 = (const float*)d_in[2];
  const float* b1 = (const float*)d_in[3];
  const float* W2 = (const float*)d_in[4];
  const float* b2 = (const float*)d_in[5];
  float* out = (float*)d_out;

  char* ws = (char*)d_ws;
  size_t off = 0;
  auto carve = [&](size_t bytes) {
    void* p = ws + off; off += (bytes + 255) & ~(size_t)255; return p;
  };
  bf16*  Tbf    = (bf16*) carve((size_t)48*32*2);
  bf16*  Abf    = (bf16*) carve((size_t)32*64*2);
  float* a1     = (float*)carve(NC*4);
  float* rs     = (float*)carve(NP*4);
  float* wv     = (float*)carve(NP*4);
  float* bb     = (float*)carve(DIM*4);
  float* scales = (float*)carve(8*4);
  float* zbias  = (float*)carve(DIM*4);
  float* y0     = (float*)carve((size_t)NELEM*4);
  float* C      = (float*)carve((size_t)NELEM*4);
  bf16*  y0bf   = (bf16*) carve((size_t)NELEM*2);
  bf16*  H1     = (bf16*) carve((size_t)NELEM*2);
  bf16*  Hw     = (bf16*) carve((size_t)NELEM*2);
  bf16*  W1T    = (bf16*) carve((size_t)DIM*DIM*2);
  bf16*  W2T    = (bf16*) carve((size_t)DIM*DIM*2);
  bf16*  W2bf   = (bf16*) carve((size_t)DIM*DIM*2);
  bf16*  W21T   = (bf16*) carve((size_t)DIM*DIM*2);
  bf16*  Pa     = (bf16*) carve((size_t)PROWS*DIM*2);
  bf16*  Pb     = (bf16*) carve((size_t)PROWS*DIM*2);

  const int ITER_LDS = 98304;   // sGT 32K + sHT 64K (staging 56K overlaid)
  hipFuncSetAttribute(reinterpret_cast<const void*>(&k_iter<0>),
                      hipFuncAttributeMaxDynamicSharedMemorySize, ITER_LDS);
  hipFuncSetAttribute(reinterpret_cast<const void*>(&k_iter<1>),
                      hipFuncAttributeMaxDynamicSharedMemorySize, ITER_LDS);
  hipFuncSetAttribute(reinterpret_cast<const void*>(&k_iter<2>),
                      hipFuncAttributeMaxDynamicSharedMemorySize, ITER_LDS);

  k_setup<<<1, 64, 0, stream>>>(t_span, Tbf, Abf, a1, rs, wv, scales, zbias, out);
  k_wt<<<(DIM*DIM)/256, 256, 0, stream>>>(W1, W2, W1T, W2T, W2bf);
  k_bb<<<2, 256, 0, stream>>>(W1, b2, bb);
  // W21T[h][i] = (W2.W1)[i][h]  (one-time 512^3 GEMM)
  k_gemm<1><<<32, 256, 0, stream>>>(W1T, W2bf, zbias, W21T, nullptr);
  k_init<<<NELEM/256, 256, 0, stream>>>(y_init, y0, y0bf, out + 7);
  // C = y0.W1 + b1 (f32), H1 = tanh(C)  -- interval 0; k_next updates afterwards
  k_gemm<2><<<16, 256, 0, stream>>>(y0bf, W1T, b1, H1, C);

  const int GRID = (BATCH/4)*(DIM/128);   // 64*4 = 256 = 1 block/CU

  for (int t = 0; t < NI; t++) {
    // Picard iter 2 (iter 1 folded via rank-1 G24): H1 -> Pa
    k_iter<0><<<GRID, 512, ITER_LDS, stream>>>(nullptr, H1, W21T, C, bb, Tbf, Abf,
                                               a1, rs, wv, scales, t, Pa);
    // iters 3,4: P -> P'
    k_iter<1><<<GRID, 512, ITER_LDS, stream>>>(Pa, nullptr, W21T, C, bb, Tbf, Abf,
                                               a1, rs, wv, scales, t, Pb);
    k_iter<1><<<GRID, 512, ITER_LDS, stream>>>(Pb, nullptr, W21T, C, bb, Tbf, Abf,
                                               a1, rs, wv, scales, t, Pa);
    // iter 5: P -> Hw
    k_iter<2><<<GRID, 512, ITER_LDS, stream>>>(Pa, nullptr, W21T, C, bb, Tbf, Abf,
                                               a1, rs, wv, scales, t, Hw);
    // y1 (traj/y0) and next interval's C/H1 in one dual-B GEMM
    k_next<<<32, 256, 0, stream>>>(Hw, W2T, W21T, b2, bb, y0, y0bf, C, H1,
                                   scales, t, out + 7 + (size_t)(t+1)*NELEM);
  }
}

// Round 14
// 392.831 us; speedup vs baseline: 1.0847x; 1.0838x over previous
//
#include <hip/hip_runtime.h>
#include <hip/hip_bf16.h>
#include <math.h>

#define NC 24
#define NP 48
#define NI 6
#define BATCH 256
#define DIM 512
#define NELEM (BATCH*DIM)     // 131072
#define PROWS (BATCH*NC)      // 6144

typedef __bf16 bf16x8 __attribute__((ext_vector_type(8)));
typedef unsigned short u16x8 __attribute__((ext_vector_type(8)));
typedef float f32x4 __attribute__((ext_vector_type(4)));
using bf16 = __hip_bfloat16;

struct bq8 { __hip_bfloat162 a, b; };   // 8-byte LDS write

__device__ __forceinline__ void gld_lds16(const void* g, void* l) {
  __builtin_amdgcn_global_load_lds(
      (const __attribute__((address_space(1))) void*)g,
      (__attribute__((address_space(3))) void*)l, 16, 0, 0);
}

__device__ __forceinline__ float fast_tanh(float x) {
  float u = __expf(2.0f * x);
  float r = __builtin_amdgcn_rcpf(u + 1.0f);
  return __builtin_fmaf(-2.0f, r, 1.0f);
}

__device__ __forceinline__ float bfu(unsigned short u) {
  union { unsigned int i; float f; } v; v.i = ((unsigned)u) << 16; return v.f;
}

// ---- k_prep1: fused {weights->bf16, init y0/traj0, bb, spectral constants} ----
// grid 1539 x 256: [0,1024) wt | [1024,1536) init | [1536,1538) bb | 1538 setup
__global__ __launch_bounds__(256) void k_prep1(
    const float* __restrict__ t_span, const float* __restrict__ W1,
    const float* __restrict__ W2, const float* __restrict__ b1,
    const float* __restrict__ b2, const float* __restrict__ y_init,
    bf16* __restrict__ Tbf, bf16* __restrict__ Abf, float* __restrict__ a1,
    float* __restrict__ rs, float* __restrict__ wv, float* __restrict__ scales,
    float* __restrict__ zbias, float* __restrict__ out,
    bf16* __restrict__ W1T, bf16* __restrict__ W2T, bf16* __restrict__ W2bf,
    float* __restrict__ bb, float* __restrict__ y0, bf16* __restrict__ y0bf) {
  int bid = blockIdx.x;
  int tid = threadIdx.x;
  if (bid < 1024) {
    int idx = bid*256 + tid;
    int k = idx >> 9, n = idx & 511;
    W1T[n*DIM + k] = __float2bfloat16(W1[idx]);
    W2T[n*DIM + k] = __float2bfloat16(W2[idx]);
    W2bf[idx]      = __float2bfloat16(W2[idx]);
  } else if (bid < 1536) {
    int i = (bid - 1024)*256 + tid;
    float v = y_init[i];
    y0[i] = v; out[7 + i] = v;            // traj[0]
    y0bf[i] = __float2bfloat16(v);
  } else if (bid < 1538) {
    int h = (bid - 1536)*256 + tid;
    float s = 0.f;
    for (int d = 0; d < DIM; d++) s = fmaf(b2[d], W1[d*DIM + h], s);
    bb[h] = s;
  } else {
    __shared__ double Tsh[NC][NP];
    __shared__ double Ashd[NC][NP];
    __shared__ double a1sh[NC];
    __shared__ double wsh[NP];
    for (int idx = tid; idx < NC*NP; idx += 256) {
      int c = idx / NP, p = idx % NP;
      Tsh[c][p] = cos((double)c * (M_PI * ((double)p + 0.5) / NP));
    }
    for (int idx = tid; idx < 32*64; idx += 256) Abf[idx] = __float2bfloat16(0.f);
    for (int idx = tid; idx < 48*32; idx += 256) Tbf[idx] = __float2bfloat16(0.f);
    __syncthreads();
    if (tid < NP) {
      int q = tid;
      double V[NC], K[NC];
      for (int c = 0; c < NC; c++) V[c] = (2.0/NP) * Tsh[c][q];
      V[0] *= 0.5;
      double s = 0.0;
      for (int n = 1; n < NC; n++) {
        double hi = (n+1 < NC) ? V[n+1] : 0.0;
        K[n] = (V[n-1] - hi) / (2.0*n);
        s += (n & 1) ? -K[n] : K[n];
      }
      K[0] = -s;
      double wsum = 0.0;
      for (int c = 0; c < NC; c++) wsum += K[c];
      wv[q] = (float)wsum;
      wsh[q] = wsum;
      for (int c = 0; c < NC; c++) {
        Ashd[c][q] = K[c];
        Abf[c*64 + q] = __float2bfloat16((float)K[c]);
      }
    }
    __syncthreads();
    if (tid < NC) {
      double s = 0.0;
      for (int q = 0; q < NP; q++) s += Ashd[tid][q];
      a1sh[tid] = s;
      a1[tid] = (float)s;
    }
    __syncthreads();
    if (tid < NP) {
      int p = tid;
      double r = 0.0;
      for (int c = 0; c < NC; c++) r += Tsh[c][p] * a1sh[c];
      rs[p] = (float)r;
      for (int c = 0; c < NC; c++) Tbf[p*32 + c] = __float2bfloat16((float)Tsh[c][p]);
    }
    if (tid == 0) {
      double s = 0.0;
      for (int q = 0; q < NP; q++) s += wsh[q];
      scales[6] = (float)s;                        // sumw
    }
    for (int idx = tid; idx < DIM; idx += 256) zbias[idx] = 0.f;
    if (tid < NI) scales[tid] = 0.5f*(t_span[tid+1]-t_span[tid]);
    if (tid < NI+1) out[tid] = t_span[tid];
  }
}

// ---- gemm_body: proven 128x64 BK=64 dbuf GEMM as device fn (virtual bid/grid) ----
// EPI 1: outb = bf16(acc + bias);  EPI 2: outf = acc+bias (f32); outb = bf16(tanh)
template<int EPI>
__device__ __forceinline__ void gemm_body(int vbid, int vgrid,
    bf16 (*sA)[128*64], bf16 (*sB)[64*64],
    const bf16* __restrict__ A, const bf16* __restrict__ BT,
    const float* __restrict__ bias, bf16* __restrict__ outb,
    float* __restrict__ outf) {
  int tid = threadIdx.x;
  int lane = tid & 63, wid = tid >> 6;
  int q8 = vgrid >> 3;
  int tl = (vbid & 7)*q8 + (vbid >> 3);
  int bm = tl >> 3, bn = tl & 7;
  int row0 = bm*128, col0 = bn*64;
  int wr = wid >> 1, wc = wid & 1;
  int r16 = lane & 15, g = lane >> 4;

  f32x4 acc[4][2];
  #pragma unroll
  for (int m = 0; m < 4; m++)
    #pragma unroll
    for (int n = 0; n < 2; n++)
      acc[m][n] = {0.f, 0.f, 0.f, 0.f};

  auto stage = [&](int buf, int k0) {
    #pragma unroll
    for (int j = 0; j < 4; j++) {
      int cid = wid*64 + lane + j*256;
      int r = cid >> 3;
      int c = (cid & 7) ^ (r & 7);
      gld_lds16(A + (size_t)(row0 + r)*DIM + k0 + c*8,
                (char*)&sA[buf][0] + wid*1024 + j*4096);
    }
    #pragma unroll
    for (int j = 0; j < 2; j++) {
      int cid = wid*64 + lane + j*256;
      int r = cid >> 3;
      int c = (cid & 7) ^ (r & 7);
      gld_lds16(BT + (size_t)(col0 + r)*DIM + k0 + c*8,
                (char*)&sB[buf][0] + wid*1024 + j*4096);
    }
  };

  stage(0, 0);
  int cur = 0;
  for (int k0 = 0; k0 < DIM; k0 += 64) {
    if (k0 + 64 < DIM) {
      stage(cur ^ 1, k0 + 64);
      asm volatile("s_waitcnt vmcnt(6)" ::: "memory");
    } else {
      asm volatile("s_waitcnt vmcnt(0)" ::: "memory");
    }
    __builtin_amdgcn_s_barrier();
    #pragma unroll
    for (int kk = 0; kk < 2; kk++) {
      bf16x8 af[4], bfr[2];
      #pragma unroll
      for (int m = 0; m < 4; m++) {
        int r = wr*64 + m*16 + r16;
        af[m] = *(const bf16x8*)(&sA[cur][0] + r*64 + (((kk*4+g) ^ (r&7))*8));
      }
      #pragma unroll
      for (int n = 0; n < 2; n++) {
        int r = wc*32 + n*16 + r16;
        bfr[n] = *(const bf16x8*)(&sB[cur][0] + r*64 + (((kk*4+g) ^ (r&7))*8));
      }
      #pragma unroll
      for (int m = 0; m < 4; m++)
        #pragma unroll
        for (int n = 0; n < 2; n++)
          acc[m][n] = __builtin_amdgcn_mfma_f32_16x16x32_bf16(af[m], bfr[n], acc[m][n], 0, 0, 0);
    }
    __builtin_amdgcn_s_barrier();
    cur ^= 1;
  }

  #pragma unroll
  for (int m = 0; m < 4; m++) {
    int rowb = row0 + wr*64 + m*16 + g*4;
    #pragma unroll
    for (int n = 0; n < 2; n++) {
      int col = col0 + wc*32 + n*16 + r16;
      float bv = bias[col];
      #pragma unroll
      for (int r = 0; r < 4; r++) {
        float v = acc[m][n][r] + bv;
        size_t idx = (size_t)(rowb + r)*DIM + col;
        if constexpr (EPI == 1) {
          outb[idx] = __float2bfloat16(v);
        } else {
          outf[idx] = v;
          outb[idx] = __float2bfloat16(fast_tanh(v));
        }
      }
    }
  }
}

// ---- k_prep2: fused {W21T = W1T.W2bf (32 vblocks), C/H1 = y0bf.W1T (16 vblocks)} ----
__global__ __launch_bounds__(256, 3) void k_prep2(
    const bf16* __restrict__ W1T, const bf16* __restrict__ W2bf,
    const float* __restrict__ zbias, bf16* __restrict__ W21T,
    const bf16* __restrict__ y0bf, const float* __restrict__ b1,
    bf16* __restrict__ H1, float* __restrict__ C) {
  __shared__ bf16 sA[2][128*64];
  __shared__ bf16 sB[2][64*64];
  if (blockIdx.x < 32)
    gemm_body<1>(blockIdx.x, 32, sA, sB, W1T, W2bf, zbias, W21T, nullptr);
  else
    gemm_body<2>(blockIdx.x - 32, 16, sA, sB, y0bf, W1T, b1, H1, C);
}

// ---- k_iter: one Picard iteration in 24-coeff space (R10-proven). Tile 2b x 128h.
// MODE 0 (FIRST): G24 = a1 (x) (H1.W21) per-thread dot; phases B,C -> P'
// MODE 1 (MID):   A: G24 = P.W21 (48x128 MFMA, 2-buf, vmcnt(6)); B; C -> P'
// MODE 2 (FIN):   A,B -> Hw = sum_p wv[p]*tanh(Z[p])
template<int MODE>
__global__ __launch_bounds__(256, 2) void k_iter(
    const bf16* __restrict__ Pin, const bf16* __restrict__ H1,
    const bf16* __restrict__ W21T, const float* __restrict__ Cg,
    const float* __restrict__ bbg, const bf16* __restrict__ Tbf,
    const bf16* __restrict__ Abf, const float* __restrict__ a1,
    const float* __restrict__ rsg, const float* __restrict__ wvg,
    const float* __restrict__ scales, int t, bf16* __restrict__ outp) {
  __shared__ char smem[49152];
  int tid = threadIdx.x;
  int lane = tid & 63, wid = tid >> 6;
  int r16 = lane & 15, g = lane >> 4;
  int q8 = gridDim.x >> 3;
  int tl = (blockIdx.x & 7)*q8 + (blockIdx.x >> 3);
  int bm = tl >> 2, bn = tl & 3;
  int col0 = bn*128;
  int bglob0 = bm*2;

  if constexpr (MODE != 0) {
    // ---- Phase A: G24 = P.W21, rows [bm*48, +48), cols [col0, +128) ----
    int row0 = bm*48;
    f32x4 acc[3][2];
    #pragma unroll
    for (int m = 0; m < 3; m++)
      #pragma unroll
      for (int n = 0; n < 2; n++)
        acc[m][n] = {0.f, 0.f, 0.f, 0.f};

    auto stage = [&](int buf, int k0) {
      #pragma unroll
      for (int j = 0; j < 2; j++) {         // A: 384 chunks = 2 x (4 waves x 48 lanes)
        if (lane < 48) {
          int cid = j*192 + wid*48 + lane;
          int r = cid >> 3, cc = (cid & 7) ^ (r & 7);
          gld_lds16(Pin + (size_t)(row0 + r)*DIM + k0 + cc*8,
                    smem + buf*6144 + j*3072 + wid*768);
        }
      }
      #pragma unroll
      for (int j = 0; j < 4; j++) {         // B: 1024 chunks = 4 x 256
        int cid = j*256 + wid*64 + lane;
        int r = cid >> 3, cc = (cid & 7) ^ (r & 7);
        gld_lds16(W21T + (size_t)(col0 + r)*DIM + k0 + cc*8,
                  smem + 12288 + buf*16384 + j*4096 + wid*1024);
      }
    };

    stage(0, 0);
    int cur = 0;
    for (int ks = 0; ks < 8; ks++) {
      if (ks < 7) {
        stage(cur ^ 1, (ks+1)*64);
        asm volatile("s_waitcnt vmcnt(6)" ::: "memory");  // 6 loads/stage (2A + 4B)
      } else {
        asm volatile("s_waitcnt vmcnt(0)" ::: "memory");
      }
      __builtin_amdgcn_s_barrier();
      const char* sAc = smem + cur*6144;
      const char* sBc = smem + 12288 + cur*16384;
      #pragma unroll
      for (int kk = 0; kk < 2; kk++) {
        bf16x8 af[3], bfr[2];
        #pragma unroll
        for (int m = 0; m < 3; m++) {
          int r = m*16 + r16;
          af[m] = *(const bf16x8*)(sAc + r*128 + ((kk*4+g) ^ (r&7))*16);
        }
        #pragma unroll
        for (int n = 0; n < 2; n++) {
          int r = wid*32 + n*16 + r16;
          bfr[n] = *(const bf16x8*)(sBc + r*128 + ((kk*4+g) ^ (r&7))*16);
        }
        #pragma unroll
        for (int m = 0; m < 3; m++)
          #pragma unroll
          for (int n = 0; n < 2; n++)
            acc[m][n] = __builtin_amdgcn_mfma_f32_16x16x32_bf16(af[m], bfr[n], acc[m][n], 0, 0, 0);
      }
      __builtin_amdgcn_s_barrier();
      cur ^= 1;
    }

    // write G24 -> sGT[b][h][c] (rows of 64B, slot swizzle)
    #pragma unroll
    for (int m = 0; m < 3; m++) {
      int rowf = m*16 + g*4;                // 4 consecutive c via regs; never crosses b
      int b_loc = rowf >= 24 ? 1 : 0;
      int c0 = rowf - b_loc*24;
      int slot = c0 >> 3;
      int inb  = (c0*2) & 15;
      #pragma unroll
      for (int n = 0; n < 2; n++) {
        int h = wid*32 + n*16 + r16;
        char* ad = smem + b_loc*8192 + h*64 + (((slot ^ ((h>>1)&3)) << 4) | inb);
        bq8 v;
        v.a = __hip_bfloat162{__float2bfloat16(acc[m][n][0]), __float2bfloat16(acc[m][n][1])};
        v.b = __hip_bfloat162{__float2bfloat16(acc[m][n][2]), __float2bfloat16(acc[m][n][3])};
        *(bq8*)ad = v;
      }
    }
  } else {
    // ---- FIRST: sH1 <- H1 rows; per-thread g1 = H1[b].W21[:,h]; sGT = a1 (x) g1 ----
    bf16* sH1 = (bf16*)(smem + 16384);
    #pragma unroll
    for (int j = 0; j < 4; j++) {
      int e = j*256 + tid;                  // [0,1024)
      int b = e >> 9, k = e & 511;
      sH1[e] = H1[(size_t)(bglob0 + b)*DIM + k];
    }
    __syncthreads();
    int b = tid >> 7, hl = tid & 127;
    int hg = col0 + hl;
    const bf16* wrow = W21T + (size_t)hg*DIM;
    const bf16* hrow = sH1 + b*512;
    float g1 = 0.f;
    for (int ks = 0; ks < 64; ks++) {
      u16x8 w8 = *(const u16x8*)(wrow + ks*8);
      u16x8 h8 = *(const u16x8*)(hrow + ks*8);
      #pragma unroll
      for (int i = 0; i < 8; i++)
        g1 = fmaf(bfu(h8[i]), bfu(w8[i]), g1);
    }
    __syncthreads();
    int rot = ((hl>>1)&3) << 4;
    #pragma unroll
    for (int c = 0; c < NC; c++) {
      int lb = c*2;
      char* ad = smem + b*8192 + hl*64 + ((( (lb>>4) << 4) ^ rot) | (lb & 15));
      *(bf16*)ad = __float2bfloat16(a1[c]*g1);
    }
  }

  // zero sGT pad slot (c 24..31) and barrier before phase B
  if (tid < 256) {
    int bz = tid >> 7, hz = tid & 127;
    *(f32x4*)(smem + bz*8192 + hz*64 + ((3 ^ ((hz>>1)&3)) << 4)) = f32x4{0.f,0.f,0.f,0.f};
  }
  __syncthreads();

  // ---- Phase B: Z = C + sc*(T48.G24 + rs*bb); tanh ----
  int b_w = wid >> 1;
  int h0 = (wid & 1) << 6;
  int bglob = bglob0 + b_w;
  float sc = scales[t];

  f32x4 acc2[3][4];
  #pragma unroll
  for (int pt = 0; pt < 3; pt++)
    #pragma unroll
    for (int n2 = 0; n2 < 4; n2++)
      acc2[pt][n2] = {0.f, 0.f, 0.f, 0.f};
  {
    bf16x8 afT[3];
    #pragma unroll
    for (int pt = 0; pt < 3; pt++)
      afT[pt] = *(const bf16x8*)(Tbf + (pt*16 + r16)*32 + g*8);
    #pragma unroll
    for (int n2 = 0; n2 < 4; n2++) {
      int h = h0 + n2*16 + r16;
      bf16x8 b8 = *(const bf16x8*)(smem + b_w*8192 + h*64 + ((g ^ ((h>>1)&3)) << 4));
      #pragma unroll
      for (int pt = 0; pt < 3; pt++)
        acc2[pt][n2] = __builtin_amdgcn_mfma_f32_16x16x32_bf16(afT[pt], b8, acc2[pt][n2], 0, 0, 0);
    }
  }

  float rsv[12];
  #pragma unroll
  for (int pt = 0; pt < 3; pt++)
    #pragma unroll
    for (int r = 0; r < 4; r++)
      rsv[pt*4+r] = rsg[pt*16 + g*4 + r];

  if constexpr (MODE == 2) {
    // FIN: Hw = sum_p wv[p]*tanh(Z[p])
    float wvv[12];
    #pragma unroll
    for (int pt = 0; pt < 3; pt++)
      #pragma unroll
      for (int r = 0; r < 4; r++)
        wvv[pt*4+r] = wvg[pt*16 + g*4 + r];
    #pragma unroll
    for (int n2 = 0; n2 < 4; n2++) {
      int hg2 = col0 + h0 + n2*16 + r16;
      float cv = Cg[(size_t)bglob*DIM + hg2];
      float bbv = bbg[hg2];
      float hw = 0.f;
      #pragma unroll
      for (int pt = 0; pt < 3; pt++)
        #pragma unroll
        for (int r = 0; r < 4; r++) {
          float z = fmaf(sc, fmaf(rsv[pt*4+r], bbv, acc2[pt][n2][r]), cv);
          hw = fmaf(wvv[pt*4+r], fast_tanh(z), hw);
        }
      hw += __shfl_xor(hw, 16);
      hw += __shfl_xor(hw, 32);
      if (g == 0)
        outp[(size_t)bglob*DIM + hg2] = __float2bfloat16(hw);
    }
    return;
  } else {
    // tanh -> sHT[b][h][p]
    #pragma unroll
    for (int n2 = 0; n2 < 4; n2++) {
      int h = h0 + n2*16 + r16;
      int hg2 = col0 + h;
      float cv = Cg[(size_t)bglob*DIM + hg2];
      float bbv = bbg[hg2];
      #pragma unroll
      for (int pt = 0; pt < 3; pt++) {
        int p0 = pt*16 + g*4;
        float th[4];
        #pragma unroll
        for (int r = 0; r < 4; r++) {
          float z = fmaf(sc, fmaf(rsv[pt*4+r], bbv, acc2[pt][n2][r]), cv);
          th[r] = fast_tanh(z);
        }
        char* ad = smem + 16384 + b_w*16384 + h*128 + ((p0*2) ^ ((h&7)<<4));
        bq8 v;
        v.a = __hip_bfloat162{__float2bfloat16(th[0]), __float2bfloat16(th[1])};
        v.b = __hip_bfloat162{__float2bfloat16(th[2]), __float2bfloat16(th[3])};
        *(bq8*)ad = v;
      }
    }
    // zero sHT pad p 48..63
    if (tid < 256) {
      int bz = tid >> 7, hz = tid & 127;
      char* base = smem + 16384 + bz*16384 + hz*128;
      *(f32x4*)(base + (96  ^ ((hz&7)<<4))) = f32x4{0.f,0.f,0.f,0.f};
      *(f32x4*)(base + (112 ^ ((hz&7)<<4))) = f32x4{0.f,0.f,0.f,0.f};
    }
    __syncthreads();

    // ---- Phase C: P' = A24.tanh(Z) ----
    f32x4 acc3[2][4];
    #pragma unroll
    for (int ct = 0; ct < 2; ct++)
      #pragma unroll
      for (int n2 = 0; n2 < 4; n2++)
        acc3[ct][n2] = {0.f, 0.f, 0.f, 0.f};
    bf16x8 afA[2][2];
    #pragma unroll
    for (int ct = 0; ct < 2; ct++)
      #pragma unroll
      for (int kk = 0; kk < 2; kk++)
        afA[ct][kk] = *(const bf16x8*)(Abf + (ct*16 + r16)*64 + kk*32 + g*8);
    #pragma unroll
    for (int kk = 0; kk < 2; kk++) {
      #pragma unroll
      for (int n2 = 0; n2 < 4; n2++) {
        int h = h0 + n2*16 + r16;
        bf16x8 b8 = *(const bf16x8*)(smem + 16384 + b_w*16384 + h*128 +
                                     ((kk*64 + g*16) ^ ((h&7)<<4)));
        #pragma unroll
        for (int ct = 0; ct < 2; ct++)
          acc3[ct][n2] = __builtin_amdgcn_mfma_f32_16x16x32_bf16(afA[ct][kk], b8, acc3[ct][n2], 0, 0, 0);
      }
    }
    #pragma unroll
    for (int n2 = 0; n2 < 4; n2++) {
      int hg2 = col0 + h0 + n2*16 + r16;
      #pragma unroll
      for (int ct = 0; ct < 2; ct++) {
        if (ct == 1 && g >= 2) continue;    // c >= 24 pad rows
        #pragma unroll
        for (int r = 0; r < 4; r++) {
          int c = ct*16 + g*4 + r;
          outp[((size_t)(bglob*NC + c))*DIM + hg2] = __float2bfloat16(acc3[ct][n2][r]);
        }
      }
    }
  }
}

// ---- k_next: A=Hw, dual-B GEMM. N-half 0 (W2T): y1/traj/y0/y0bf.
//      N-half 1 (W21T): C += sc*acc + sc*sumw*bb ; H1 = bf16(tanh(C')) ----
__global__ __launch_bounds__(256, 3) void k_next(const bf16* __restrict__ A,
    const bf16* __restrict__ W2T, const bf16* __restrict__ W21T,
    const float* __restrict__ b2, const float* __restrict__ bb,
    float* __restrict__ y0, bf16* __restrict__ y0bf, float* __restrict__ C,
    bf16* __restrict__ H1, const float* __restrict__ scales, int t,
    float* __restrict__ traj) {
  __shared__ bf16 sA[2][128*64];
  __shared__ bf16 sB[2][64*64];
  int tid = threadIdx.x;
  int lane = tid & 63, wid = tid >> 6;
  int q8 = gridDim.x >> 3;                    // 4
  int tl = (blockIdx.x & 7)*q8 + (blockIdx.x >> 3);
  int bm = tl >> 4, bn = tl & 15;
  int half = bn >> 3;                         // 0: W2T, 1: W21T
  int row0 = bm*128, col0 = (bn & 7)*64;
  const bf16* BT = half ? W21T : W2T;
  int wr = wid >> 1, wc = wid & 1;
  int r16 = lane & 15, g = lane >> 4;

  f32x4 acc[4][2];
  #pragma unroll
  for (int m = 0; m < 4; m++)
    #pragma unroll
    for (int n = 0; n < 2; n++)
      acc[m][n] = {0.f, 0.f, 0.f, 0.f};

  auto stage = [&](int buf, int k0) {
    #pragma unroll
    for (int j = 0; j < 4; j++) {
      int cid = wid*64 + lane + j*256;
      int r = cid >> 3;
      int c = (cid & 7) ^ (r & 7);
      gld_lds16(A + (size_t)(row0 + r)*DIM + k0 + c*8,
                (char*)&sA[buf][0] + wid*1024 + j*4096);
    }
    #pragma unroll
    for (int j = 0; j < 2; j++) {
      int cid = wid*64 + lane + j*256;
      int r = cid >> 3;
      int c = (cid & 7) ^ (r & 7);
      gld_lds16(BT + (size_t)(col0 + r)*DIM + k0 + c*8,
                (char*)&sB[buf][0] + wid*1024 + j*4096);
    }
  };

  stage(0, 0);
  int cur = 0;
  for (int k0 = 0; k0 < DIM; k0 += 64) {
    if (k0 + 64 < DIM) {
      stage(cur ^ 1, k0 + 64);
      asm volatile("s_waitcnt vmcnt(6)" ::: "memory");
    } else {
      asm volatile("s_waitcnt vmcnt(0)" ::: "memory");
    }
    __builtin_amdgcn_s_barrier();
    #pragma unroll
    for (int kk = 0; kk < 2; kk++) {
      bf16x8 af[4], bfr[2];
      #pragma unroll
      for (int m = 0; m < 4; m++) {
        int r = wr*64 + m*16 + r16;
        af[m] = *(const bf16x8*)(&sA[cur][0] + r*64 + (((kk*4+g) ^ (r&7))*8));
      }
      #pragma unroll
      for (int n = 0; n < 2; n++) {
        int r = wc*32 + n*16 + r16;
        bfr[n] = *(const bf16x8*)(&sB[cur][0] + r*64 + (((kk*4+g) ^ (r&7))*8));
      }
      #pragma unroll
      for (int m = 0; m < 4; m++)
        #pragma unroll
        for (int n = 0; n < 2; n++)
          acc[m][n] = __builtin_amdgcn_mfma_f32_16x16x32_bf16(af[m], bfr[n], acc[m][n], 0, 0, 0);
    }
    __builtin_amdgcn_s_barrier();
    cur ^= 1;
  }

  float sc = scales[t];
  float sumw = scales[6];
  #pragma unroll
  for (int m = 0; m < 4; m++) {
    int rowb = row0 + wr*64 + m*16 + g*4;
    #pragma unroll
    for (int n = 0; n < 2; n++) {
      int col = col0 + wc*32 + n*16 + r16;
      #pragma unroll
      for (int r = 0; r < 4; r++) {
        size_t idx = (size_t)(rowb + r)*DIM + col;
        if (half == 0) {
          float bv = sumw * b2[col];
          float y1 = fmaf(sc, acc[m][n][r] + bv, y0[idx]);
          y0[idx] = y1;
          y0bf[idx] = __float2bfloat16(y1);
          traj[idx] = y1;
        } else {
          float cb = sc * sumw * bb[col];
          float cnew = fmaf(sc, acc[m][n][r], C[idx] + cb);
          C[idx] = cnew;
          H1[idx] = __float2bfloat16(fast_tanh(cnew));
        }
      }
    }
  }
}

extern "C" void kernel_launch(void* const* d_in, const int* in_sizes, int n_in,
                              void* d_out, int out_size, void* d_ws, size_t ws_size,
                              hipStream_t stream) {
  const float* y_init = (const float*)d_in[0];
  const float* t_span = (const float*)d_in[1];
  const float* W1 = (const float*)d_in[2];
  const float* b1 = (const float*)d_in[3];
  const float* W2 = (const float*)d_in[4];
  const float* b2 = (const float*)d_in[5];
  float* out = (float*)d_out;

  char* ws = (char*)d_ws;
  size_t off = 0;
  auto carve = [&](size_t bytes) {
    void* p = ws + off; off += (bytes + 255) & ~(size_t)255; return p;
  };
  bf16*  Tbf    = (bf16*) carve((size_t)48*32*2);
  bf16*  Abf    = (bf16*) carve((size_t)32*64*2);
  float* a1     = (float*)carve(NC*4);
  float* rs     = (float*)carve(NP*4);
  float* wv     = (float*)carve(NP*4);
  float* bb     = (float*)carve(DIM*4);
  float* scales = (float*)carve(8*4);
  float* zbias  = (float*)carve(DIM*4);
  float* y0     = (float*)carve((size_t)NELEM*4);
  float* C      = (float*)carve((size_t)NELEM*4);
  bf16*  y0bf   = (bf16*) carve((size_t)NELEM*2);
  bf16*  H1     = (bf16*) carve((size_t)NELEM*2);
  bf16*  Hw     = (bf16*) carve((size_t)NELEM*2);
  bf16*  W1T    = (bf16*) carve((size_t)DIM*DIM*2);
  bf16*  W2T    = (bf16*) carve((size_t)DIM*DIM*2);
  bf16*  W2bf   = (bf16*) carve((size_t)DIM*DIM*2);
  bf16*  W21T   = (bf16*) carve((size_t)DIM*DIM*2);
  bf16*  Pa     = (bf16*) carve((size_t)PROWS*DIM*2);
  bf16*  Pb     = (bf16*) carve((size_t)PROWS*DIM*2);

  // fused setup: layer 1 (independent) then layer 2 (the two small GEMMs)
  k_prep1<<<1539, 256, 0, stream>>>(t_span, W1, W2, b1, b2, y_init,
      Tbf, Abf, a1, rs, wv, scales, zbias, out, W1T, W2T, W2bf, bb, y0, y0bf);
  k_prep2<<<48, 256, 0, stream>>>(W1T, W2bf, zbias, W21T, y0bf, b1, H1, C);

  const int GRID = (BATCH/2)*(DIM/128);   // 128*4 = 512 = 2/CU

  for (int t = 0; t < NI; t++) {
    // Picard iter 2 (iter 1 folded via rank-1 G24): H1 -> Pa
    k_iter<0><<<GRID, 256, 0, stream>>>(nullptr, H1, W21T, C, bb, Tbf, Abf,
                                        a1, rs, wv, scales, t, Pa);
    // iters 3,4: P -> P'
    k_iter<1><<<GRID, 256, 0, stream>>>(Pa, nullptr, W21T, C, bb, Tbf, Abf,
                                        a1, rs, wv, scales, t, Pb);
    k_iter<1><<<GRID, 256, 0, stream>>>(Pb, nullptr, W21T, C, bb, Tbf, Abf,
                                        a1, rs, wv, scales, t, Pa);
    // iter 5: P -> Hw
    k_iter<2><<<GRID, 256, 0, stream>>>(Pa, nullptr, W21T, C, bb, Tbf, Abf,
                                        a1, rs, wv, scales, t, Hw);
    // y1 (traj/y0) and next interval's C/H1 in one dual-B GEMM
    k_next<<<32, 256, 0, stream>>>(Hw, W2T, W21T, b2, bb, y0, y0bf, C, H1,
                                   scales, t, out + 7 + (size_t)(t+1)*NELEM);
  }
}